// Round 6
// baseline (302.267 us; speedup 1.0000x reference)
//
#include <hip/hip_runtime.h>
#include <hip/hip_bf16.h>
#include <math.h>

// MoE: B=2,S=1024,D=1024,E=8,H=3584, top-1 routing.
// router(+x->bf16) -> aux -> scatter
//  -> ggemm<GATHER>  : g1=x@W1^T, g2=x@W2^T  (grid z=16: weights read ONCE,
//                      each block loops all M-subtiles of its expert)
//  -> swiglu (in-place into g1 -> h)
//  -> ggemm<ATOMIC>  : out += h@W3^T (split-K=4, atomicAdd f32)
// Per K-step (BK=32): A via global_load_lds (contiguous 1KB wave tiles,
// conflict-free), B reg-staged f32->bf16 2-deep, counted-vmcnt barriers.

#define NS 1024
#define ND 1024
#define NE 8
#define NH 3584
#define NTOK 2048
#define MTILES 6
#define CHUNK (MTILES * 64)   // 384 rows per chunk

typedef float f32x4 __attribute__((ext_vector_type(4)));
typedef __bf16 bf16x8 __attribute__((ext_vector_type(8)));
typedef unsigned short u16x8 __attribute__((ext_vector_type(8)));

// counted barrier: retire all but the newest N VMEM ops, publish LDS writes.
#define CBAR(N) asm volatile("s_waitcnt vmcnt(" #N ") lgkmcnt(0)\n\ts_barrier" ::: "memory")

__device__ __forceinline__ unsigned short f2b(float f) {
  return __builtin_bit_cast(unsigned short, (__bf16)f);
}

__device__ __forceinline__ void gl_lds16(const void* g, void* l) {
  __builtin_amdgcn_global_load_lds(
      (const __attribute__((address_space(1))) unsigned int*)g,
      (__attribute__((address_space(3))) unsigned int*)l, 16, 0, 0);
}

// ---------------- router (+ x f32 -> bf16) ----------------
__global__ __launch_bounds__(256) void router_kernel(
    const float* __restrict__ x, const float* __restrict__ Wr,
    float* __restrict__ probs, float* __restrict__ lse,
    int* __restrict__ counts, int* __restrict__ expert_of,
    unsigned short* __restrict__ xb)
{
  int n = blockIdx.x;
  int t = threadIdx.x;
  const float* xr = x + (size_t)n * ND;
  float xv[4];
#pragma unroll
  for (int j = 0; j < 4; ++j) xv[j] = xr[t + j * 256];
#pragma unroll
  for (int j = 0; j < 4; ++j)
    xb[(size_t)n * ND + t + j * 256] = f2b(xv[j]);
  float p[NE];
#pragma unroll
  for (int e = 0; e < NE; ++e) p[e] = 0.f;
#pragma unroll
  for (int j = 0; j < 4; ++j) {
    int d = t + j * 256;
#pragma unroll
    for (int e = 0; e < NE; ++e) p[e] += xv[j] * Wr[e * ND + d];
  }
#pragma unroll
  for (int e = 0; e < NE; ++e) {
#pragma unroll
    for (int o = 32; o > 0; o >>= 1) p[e] += __shfl_down(p[e], o, 64);
  }
  __shared__ float red[4][NE];
  int wid = t >> 6, lane = t & 63;
  if (lane == 0) {
#pragma unroll
    for (int e = 0; e < NE; ++e) red[wid][e] = p[e];
  }
  __syncthreads();
  if (t == 0) {
    float lg[NE];
#pragma unroll
    for (int e = 0; e < NE; ++e) lg[e] = red[0][e] + red[1][e] + red[2][e] + red[3][e];
    float m = lg[0]; int arg = 0;
#pragma unroll
    for (int e = 1; e < NE; ++e) if (lg[e] > m) { m = lg[e]; arg = e; }
    float s = 0.f, ex[NE];
#pragma unroll
    for (int e = 0; e < NE; ++e) { ex[e] = expf(lg[e] - m); s += ex[e]; }
    float inv = 1.f / s;
#pragma unroll
    for (int e = 0; e < NE; ++e) probs[n * NE + e] = ex[e] * inv;
    lse[n] = m + logf(s);
    expert_of[n] = arg;
    atomicAdd(&counts[arg], 1);
  }
}

// ---------------- aux losses + offsets ----------------
__global__ __launch_bounds__(256) void aux_offsets_kernel(
    const float* __restrict__ probs, const float* __restrict__ lse,
    const int* __restrict__ counts, int* __restrict__ offsets,
    int* __restrict__ cursors, float* __restrict__ out_aux)
{
  int t = threadIdx.x;
  float lsum = 0.f;
  for (int n = t; n < NTOK; n += 256) lsum += lse[n];
  float esum = 0.f, esq = 0.f;
  for (int i = t; i < NS * NE; i += 256) {
    float v = probs[i] + probs[NS * NE + i];
    esum += v; esq += v * v;
  }
  __shared__ float rb[3][4];
  int wid = t >> 6, lane = t & 63;
#pragma unroll
  for (int o = 32; o > 0; o >>= 1) {
    lsum += __shfl_down(lsum, o, 64);
    esum += __shfl_down(esum, o, 64);
    esq  += __shfl_down(esq, o, 64);
  }
  if (lane == 0) { rb[0][wid] = lsum; rb[1][wid] = esum; rb[2][wid] = esq; }
  __syncthreads();
  if (t == 0) {
    lsum = rb[0][0] + rb[0][1] + rb[0][2] + rb[0][3];
    esum = rb[1][0] + rb[1][1] + rb[1][2] + rb[1][3];
    esq  = rb[2][0] + rb[2][1] + rb[2][2] + rb[2][3];
    float zmean = lsum / (float)NTOK;
    float z_loss = zmean * zmean;
    const float nn = (float)(NS * NE);
    float mean = esum / nn;
    float var = (esq - esum * esum / nn) / (nn - 1.0f);
    float load_loss = var / (mean * mean);
    out_aux[0] = 1e-3f * z_loss + 1e-3f * load_loss;
    int off = 0;
#pragma unroll
    for (int e = 0; e < NE; ++e) { offsets[e] = off; cursors[e] = off; off += counts[e]; }
    offsets[NE] = off;
  }
}

// ---------------- token lists ----------------
__global__ __launch_bounds__(256) void scatter_kernel(
    const int* __restrict__ expert_of, int* __restrict__ cursors,
    int* __restrict__ token_list)
{
  int n = blockIdx.x * 256 + threadIdx.x;
  int e = expert_of[n];
  int p = atomicAdd(&cursors[e], 1);
  token_list[p] = n;
}

// ---------------- grouped GEMM, weights-read-once ----------------
// Block = one (expert, 64 output cols, [K-slice]) weight panel.
// M handled as MTILES(6) x 64-row subtiles per chunk (covers cnt<=384; chunk
// loop for more). 4 waves as (m-parity p, n-half q); per wave 3 subtiles x
// 64rows x 32cols. BK=32.
template<int NSTEP, bool GATHER, bool ATOMIC>
__global__ __launch_bounds__(256) void ggemm(
    const unsigned short* __restrict__ Ab, int lda,
    const float* __restrict__ Wa, const float* __restrict__ Wb, int ldw,
    const int* __restrict__ offsets, const int* __restrict__ token_list,
    unsigned short* __restrict__ ga, unsigned short* __restrict__ gb,
    float* __restrict__ outp)
{
  int e, akoff;
  const float* W;
  unsigned short* gout;
  if constexpr (GATHER) {
    e = blockIdx.z & 7;
    W = (blockIdx.z & 8) ? Wb : Wa;
    gout = (blockIdx.z & 8) ? gb : ga;
    akoff = 0;
  } else {
    e = blockIdx.z; W = Wa; gout = nullptr;
    akoff = blockIdx.y * (NSTEP * 32);
  }
  int base = offsets[e], cnt = offsets[e + 1] - base;
  if (cnt <= 0) return;
  int n0 = blockIdx.x * 64;
  const float* Wp = W + (size_t)e * ((size_t)NH * ND) + (size_t)n0 * ldw + akoff;

  __shared__ __align__(16) unsigned short As[2][MTILES][64][32];  // 48 KB
  __shared__ __align__(16) unsigned short Bs[2][64][32];          // 8 KB
  __shared__ int rtk[CHUNK];

  int t = threadIdx.x;
  int l = t & 63, w = t >> 6;
  int rl = l & 15, rq = l >> 4;   // frag row-in-16 ; k-chunk / reg-quad
  int p = w >> 1, q = w & 1;

  const float* bp = Wp + (size_t)(t >> 2) * ldw + (t & 3) * 8;

  for (int c0 = 0; c0 < cnt; c0 += CHUNK) {
    __syncthreads();
    for (int r = t; r < CHUNK; r += 256) {
      int mc = c0 + r; if (mc > cnt - 1) mc = cnt - 1;
      rtk[r] = token_list[base + mc];
    }
    __syncthreads();

    // per-thread DMA source pointers, 6 subtiles (16 rows x 64B per issue)
    const char* aSrc[MTILES];
    {
      int r16 = l >> 2, cb = l & 3;
#pragma unroll
      for (int s = 0; s < MTILES; ++s) {
        int rr_ = s * 64 + w * 16 + r16;
        size_t row;
        if constexpr (GATHER) {
          row = (size_t)rtk[rr_];
        } else {
          int mc = c0 + rr_; if (mc > cnt - 1) mc = cnt - 1;
          row = (size_t)(base + mc);
        }
        aSrc[s] = (const char*)(Ab + row * lda + akoff) + cb * 16;
      }
    }

    auto stageA = [&](int buf, int k) {
      char* d = ((char*)&As[0][0][0][0]) + buf * (MTILES * 4096) + w * 1024;
      int kb = k * 64;
#pragma unroll
      for (int s = 0; s < MTILES; ++s)
        gl_lds16(aSrc[s] + kb, d + s * 4096);
      __builtin_amdgcn_sched_barrier(0);   // pin DMA before B-loads (FIFO vmcnt)
    };

    f32x4 sA0, sA1, sB0, sB1;
    auto loadBA = [&](int k) {
      sA0 = *(const f32x4*)(bp + k * 32);
      sA1 = *(const f32x4*)(bp + k * 32 + 4);
    };
    auto loadBB = [&](int k) {
      sB0 = *(const f32x4*)(bp + k * 32);
      sB1 = *(const f32x4*)(bp + k * 32 + 4);
    };
    auto writeB = [&](int buf, const f32x4& v0, const f32x4& v1) {
      u16x8 o;
      o[0] = f2b(v0[0]); o[1] = f2b(v0[1]); o[2] = f2b(v0[2]); o[3] = f2b(v0[3]);
      o[4] = f2b(v1[0]); o[5] = f2b(v1[1]); o[6] = f2b(v1[2]); o[7] = f2b(v1[3]);
      *(u16x8*)(((char*)&Bs[0][0][0]) + buf * 4096 + (t >> 2) * 64 + (t & 3) * 16) = o;
    };

    f32x4 acc[3][4][2] = {};

    auto domfma = [&](int buf) {
      const char* Bb = ((const char*)&Bs[0][0][0]) + buf * 4096;
      bf16x8 bf0 = *(const bf16x8*)(Bb + (q * 32 + rl) * 64 + rq * 16);
      bf16x8 bf1 = *(const bf16x8*)(Bb + (q * 32 + 16 + rl) * 64 + rq * 16);
      const char* Abase = ((const char*)&As[0][0][0][0]) + buf * (MTILES * 4096);
#pragma unroll
      for (int sl = 0; sl < 3; ++sl) {
        const char* sb = Abase + (p + 2 * sl) * 4096;
#pragma unroll
        for (int i = 0; i < 4; ++i) {
          bf16x8 af = *(const bf16x8*)(sb + (i * 16 + rl) * 64 + rq * 16);
          acc[sl][i][0] = __builtin_amdgcn_mfma_f32_16x16x32_bf16(af, bf0, acc[sl][i][0], 0, 0, 0);
          acc[sl][i][1] = __builtin_amdgcn_mfma_f32_16x16x32_bf16(af, bf1, acc[sl][i][1], 0, 0, 0);
        }
      }
    };

    // prologue
    stageA(0, 0);
    loadBA(0);
    loadBB(1);
    writeB(0, sA0, sA1);
    __syncthreads();

    int buf = 0;
    for (int k = 0; k < NSTEP - 2; k += 2) {
      stageA(buf ^ 1, k + 1);
      loadBA(k + 2);
      domfma(buf);
      writeB(buf ^ 1, sB0, sB1);
      CBAR(2);
      buf ^= 1;
      stageA(buf ^ 1, k + 2);
      loadBB(k + 3);
      domfma(buf);
      writeB(buf ^ 1, sA0, sA1);
      CBAR(2);
      buf ^= 1;
    }
    // peeled final pair-half: stage A(NSTEP-1), compute NSTEP-2, then NSTEP-1
    stageA(buf ^ 1, NSTEP - 1);
    domfma(buf);
    writeB(buf ^ 1, sB0, sB1);
    CBAR(0);
    domfma(buf ^ 1);

    // epilogue
#pragma unroll
    for (int sl = 0; sl < 3; ++sl) {
      int s = p + 2 * sl;
#pragma unroll
      for (int i = 0; i < 4; ++i) {
#pragma unroll
        for (int r2 = 0; r2 < 4; ++r2) {
          int mrel = s * 64 + i * 16 + rq * 4 + r2;
          int m = c0 + mrel;
          if (m < cnt) {
#pragma unroll
            for (int j = 0; j < 2; ++j) {
              int col = n0 + q * 32 + j * 16 + rl;
              float v = acc[sl][i][j][r2];
              if constexpr (ATOMIC) {
                atomicAdd(&outp[(size_t)rtk[mrel] * ND + col], v);
              } else {
                gout[(size_t)(base + m) * NH + col] = f2b(v);
              }
            }
          }
        }
      }
    }
  }
}

// ---------------- SwiGLU in-place: g1 <- silu(g1)*g2 ----------------
__global__ __launch_bounds__(256) void swiglu_kernel(
    unsigned short* __restrict__ g1, const unsigned short* __restrict__ g2)
{
  size_t i = ((size_t)blockIdx.x * 256 + threadIdx.x) * 8;
  u16x8 a = *(const u16x8*)(g1 + i);
  u16x8 b = *(const u16x8*)(g2 + i);
  u16x8 o;
#pragma unroll
  for (int j = 0; j < 8; ++j) {
    float av = __builtin_bit_cast(float, (unsigned int)a[j] << 16);
    float bv = __builtin_bit_cast(float, (unsigned int)b[j] << 16);
    o[j] = f2b(av / (1.f + expf(-av)) * bv);
  }
  *(u16x8*)(g1 + i) = o;
}

extern "C" void kernel_launch(void* const* d_in, const int* in_sizes, int n_in,
                              void* d_out, int out_size, void* d_ws, size_t ws_size,
                              hipStream_t stream)
{
  (void)in_sizes; (void)n_in; (void)out_size; (void)ws_size;
  const float* x  = (const float*)d_in[0];
  const float* Wr = (const float*)d_in[1];
  const float* W1 = (const float*)d_in[2];
  const float* W2 = (const float*)d_in[3];
  const float* W3 = (const float*)d_in[4];
  float* out = (float*)d_out;

  char* w = (char*)d_ws;
  float* probs    = (float*)(w + 0);        // 65536 B
  float* lse      = (float*)(w + 65536);    // 8192 B
  int* counts     = (int*)(w + 73728);      // 32 B
  int* cursors    = (int*)(w + 73760);      // 32 B
  int* offsets    = (int*)(w + 73792);      // 64 B
  int* expert_of  = (int*)(w + 73856);      // 8192 B
  int* token_list = (int*)(w + 82048);      // 8192 B
  unsigned short* g1 = (unsigned short*)(w + 131072);            // 14680064 B (becomes h)
  unsigned short* g2 = g1 + (size_t)NTOK * NH;                   // 14680064 B
  unsigned short* xb = (unsigned short*)((char*)g2 + (size_t)NTOK * NH * 2); // 4 MB

  hipMemsetAsync(counts, 0, 32, stream);
  hipMemsetAsync(out, 0, (size_t)NTOK * ND * sizeof(float), stream);
  router_kernel<<<NTOK, 256, 0, stream>>>(x, Wr, probs, lse, counts, expert_of, xb);
  aux_offsets_kernel<<<1, 256, 0, stream>>>(probs, lse, counts, offsets, cursors,
                                            out + (size_t)NTOK * ND);
  scatter_kernel<<<NTOK / 256, 256, 0, stream>>>(expert_of, cursors, token_list);
  // g1 = x@W1^T, g2 = x@W2^T : weights read once, z = 16 (matrix, expert)
  ggemm<ND / 32, true, false><<<dim3(NH / 64, 1, 16), 256, 0, stream>>>(
      xb, ND, W1, W2, ND, offsets, token_list, g1, g2, nullptr);
  swiglu_kernel<<<(NTOK * NH) / (256 * 8), 256, 0, stream>>>(g1, g2);
  // out += h@W3^T : split-K=4
  ggemm<(NH / 4) / 32, false, true><<<dim3(ND / 64, 4, NE), 256, 0, stream>>>(
      g1, NH, W3, nullptr, NH, offsets, token_list, nullptr, nullptr, out);
}

// Round 7
// 221.493 us; speedup vs baseline: 1.3647x; 1.3647x over previous
//
#include <hip/hip_runtime.h>
#include <hip/hip_bf16.h>
#include <math.h>

// MoE: B=2,S=1024,D=1024,E=8,H=3584, top-1 routing.
// router(+x->bf16) -> aux -> scatter
//   -> gemm12 (x@W1^T & x@W2^T fused + SwiGLU -> h bf16)
//   -> gemm3  (h@W3^T, split-K=2, atomicAdd f32 -> out)
// GEMMs: 128x128(BN64 fused pair) x BK=64, 4 waves 2x2, bf16 MFMA 16x16x32.
// ALL staging through registers (A 2-deep, B 3-deep rotating sets, full K
// unroll -> static set indices), LDS dbuf with XOR-8 swizzle (no pads).
// Barriers are lgkmcnt-only ("s_waitcnt lgkmcnt(0); s_barrier"): vmem loads
// stay in flight across barriers; the only vmem waits are compiler-counted
// waits at each ds_write (set age ~2.3 phases for B = full HBM cover).

#define NS 1024
#define ND 1024
#define NE 8
#define NH 3584
#define NTOK 2048

typedef float f32x4 __attribute__((ext_vector_type(4)));
typedef __bf16 bf16x8 __attribute__((ext_vector_type(8)));
typedef unsigned short u16x8 __attribute__((ext_vector_type(8)));
typedef unsigned int u32x4 __attribute__((ext_vector_type(4)));

#define LBAR() asm volatile("s_waitcnt lgkmcnt(0)\n\ts_barrier" ::: "memory")

__device__ __forceinline__ unsigned short f2b(float f) {
  return __builtin_bit_cast(unsigned short, (__bf16)f);
}
__device__ __forceinline__ u16x8 cvt8(f32x4 a, f32x4 b) {
  u16x8 r;
  r[0] = f2b(a[0]); r[1] = f2b(a[1]); r[2] = f2b(a[2]); r[3] = f2b(a[3]);
  r[4] = f2b(b[0]); r[5] = f2b(b[1]); r[6] = f2b(b[2]); r[7] = f2b(b[3]);
  return r;
}

// ---------------- router (+ x f32 -> bf16) ----------------
__global__ __launch_bounds__(256) void router_kernel(
    const float* __restrict__ x, const float* __restrict__ Wr,
    float* __restrict__ probs, float* __restrict__ lse,
    int* __restrict__ counts, int* __restrict__ expert_of,
    unsigned short* __restrict__ xb)
{
  int n = blockIdx.x;
  int t = threadIdx.x;
  const float* xr = x + (size_t)n * ND;
  float xv[4];
#pragma unroll
  for (int j = 0; j < 4; ++j) xv[j] = xr[t + j * 256];
#pragma unroll
  for (int j = 0; j < 4; ++j)
    xb[(size_t)n * ND + t + j * 256] = f2b(xv[j]);
  float p[NE];
#pragma unroll
  for (int e = 0; e < NE; ++e) p[e] = 0.f;
#pragma unroll
  for (int j = 0; j < 4; ++j) {
    int d = t + j * 256;
#pragma unroll
    for (int e = 0; e < NE; ++e) p[e] += xv[j] * Wr[e * ND + d];
  }
#pragma unroll
  for (int e = 0; e < NE; ++e) {
#pragma unroll
    for (int o = 32; o > 0; o >>= 1) p[e] += __shfl_down(p[e], o, 64);
  }
  __shared__ float red[4][NE];
  int wid = t >> 6, lane = t & 63;
  if (lane == 0) {
#pragma unroll
    for (int e = 0; e < NE; ++e) red[wid][e] = p[e];
  }
  __syncthreads();
  if (t == 0) {
    float lg[NE];
#pragma unroll
    for (int e = 0; e < NE; ++e) lg[e] = red[0][e] + red[1][e] + red[2][e] + red[3][e];
    float m = lg[0]; int arg = 0;
#pragma unroll
    for (int e = 1; e < NE; ++e) if (lg[e] > m) { m = lg[e]; arg = e; }
    float s = 0.f, ex[NE];
#pragma unroll
    for (int e = 0; e < NE; ++e) { ex[e] = expf(lg[e] - m); s += ex[e]; }
    float inv = 1.f / s;
#pragma unroll
    for (int e = 0; e < NE; ++e) probs[n * NE + e] = ex[e] * inv;
    lse[n] = m + logf(s);
    expert_of[n] = arg;
    atomicAdd(&counts[arg], 1);
  }
}

// ---------------- aux losses + offsets ----------------
__global__ __launch_bounds__(256) void aux_offsets_kernel(
    const float* __restrict__ probs, const float* __restrict__ lse,
    const int* __restrict__ counts, int* __restrict__ offsets,
    int* __restrict__ cursors, float* __restrict__ out_aux)
{
  int t = threadIdx.x;
  float lsum = 0.f;
  for (int n = t; n < NTOK; n += 256) lsum += lse[n];
  float esum = 0.f, esq = 0.f;
  for (int i = t; i < NS * NE; i += 256) {
    float v = probs[i] + probs[NS * NE + i];
    esum += v; esq += v * v;
  }
  __shared__ float rb[3][4];
  int wid = t >> 6, lane = t & 63;
#pragma unroll
  for (int o = 32; o > 0; o >>= 1) {
    lsum += __shfl_down(lsum, o, 64);
    esum += __shfl_down(esum, o, 64);
    esq  += __shfl_down(esq, o, 64);
  }
  if (lane == 0) { rb[0][wid] = lsum; rb[1][wid] = esum; rb[2][wid] = esq; }
  __syncthreads();
  if (t == 0) {
    lsum = rb[0][0] + rb[0][1] + rb[0][2] + rb[0][3];
    esum = rb[1][0] + rb[1][1] + rb[1][2] + rb[1][3];
    esq  = rb[2][0] + rb[2][1] + rb[2][2] + rb[2][3];
    float zmean = lsum / (float)NTOK;
    float z_loss = zmean * zmean;
    const float nn = (float)(NS * NE);
    float mean = esum / nn;
    float var = (esq - esum * esum / nn) / (nn - 1.0f);
    float load_loss = var / (mean * mean);
    out_aux[0] = 1e-3f * z_loss + 1e-3f * load_loss;
    int off = 0;
#pragma unroll
    for (int e = 0; e < NE; ++e) { offsets[e] = off; cursors[e] = off; off += counts[e]; }
    offsets[NE] = off;
  }
}

// ---------------- token lists ----------------
__global__ __launch_bounds__(256) void scatter_kernel(
    const int* __restrict__ expert_of, int* __restrict__ cursors,
    int* __restrict__ token_list)
{
  int n = blockIdx.x * 256 + threadIdx.x;
  int e = expert_of[n];
  int p = atomicAdd(&cursors[e], 1);
  token_list[p] = n;
}

// ---------------- fused GEMM12 + SwiGLU ----------------
__global__ __launch_bounds__(256, 2) void moe_gemm12(
    const unsigned short* __restrict__ xb, const float* __restrict__ W1f,
    const float* __restrict__ W2f, const int* __restrict__ offsets,
    const int* __restrict__ token_list, unsigned short* __restrict__ h)
{
  const int e = blockIdx.z;
  const int base = offsets[e], cnt = offsets[e + 1] - base;
  const int m0 = blockIdx.y * 128;
  if (m0 >= cnt) return;
  const int n0 = blockIdx.x * 64;

  __shared__ __align__(16) unsigned short As[2][128][64];
  __shared__ __align__(16) unsigned short B1s[2][64][64];
  __shared__ __align__(16) unsigned short B2s[2][64][64];
  __shared__ int rtk[128];

  const int t = threadIdx.x;
  const int l = t & 63, w = t >> 6;
  if (t < 128) {
    int mc = m0 + t; if (mc > cnt - 1) mc = cnt - 1;
    rtk[t] = token_list[base + mc];
  }
  __syncthreads();

  // A staging map: row ar = t>>1; 4 16B-blocks sub = (t&1)*4 + i; XOR-8 swizzle
  const int ar = t >> 1;
  const int asub0 = (t & 1) * 4;
  const unsigned short* asrc = xb + (size_t)rtk[ar] * ND + asub0 * 8;
  int aw[4];
#pragma unroll
  for (int i = 0; i < 4; ++i)
    aw[i] = ar * 64 + (((asub0 + i) ^ (ar & 7)) * 8);

  // B staging map: row br = t>>2; f32 cols (t&3)*16..+15; two 16B out-blocks
  const int br = t >> 2;
  const int bcol = (t & 3) * 16;
  const float* b1p = W1f + (size_t)e * NH * ND + (size_t)(n0 + br) * ND + bcol;
  const float* b2p = W2f + (size_t)e * NH * ND + (size_t)(n0 + br) * ND + bcol;
  int bw[2];
#pragma unroll
  for (int i = 0; i < 2; ++i)
    bw[i] = br * 64 + ((((t & 3) * 2 + i) ^ (br & 7)) * 8);

  u32x4 av[2][4];
  f32x4 bv1[3][4], bv2[3][4];

  auto loadA = [&](int s, int k) {
#pragma unroll
    for (int i = 0; i < 4; ++i)
      av[s][i] = *(const u32x4*)(asrc + k * 64 + i * 8);
  };
  auto loadB = [&](int s, int k) {
#pragma unroll
    for (int i = 0; i < 4; ++i) {
      bv1[s][i] = *(const f32x4*)(b1p + k * 64 + i * 4);
      bv2[s][i] = *(const f32x4*)(b2p + k * 64 + i * 4);
    }
  };
  auto writeA = [&](int buf, int s) {
    unsigned short* dst = &As[buf][0][0];
#pragma unroll
    for (int i = 0; i < 4; ++i)
      *(u32x4*)(dst + aw[i]) = av[s][i];
  };
  auto writeB = [&](int buf, int s) {
    unsigned short* d1 = &B1s[buf][0][0];
    unsigned short* d2 = &B2s[buf][0][0];
    *(u16x8*)(d1 + bw[0]) = cvt8(bv1[s][0], bv1[s][1]);
    *(u16x8*)(d1 + bw[1]) = cvt8(bv1[s][2], bv1[s][3]);
    *(u16x8*)(d2 + bw[0]) = cvt8(bv2[s][0], bv2[s][1]);
    *(u16x8*)(d2 + bw[1]) = cvt8(bv2[s][2], bv2[s][3]);
  };

  const int wm = (w >> 1) * 64;
  const int wn = (w & 1) * 32;
  const int rl = l & 15, rq = l >> 4;
  f32x4 acc1[4][2] = {}, acc2[4][2] = {};

  auto domfma = [&](int buf) {
#pragma unroll
    for (int kk = 0; kk < 2; ++kk) {
      const int g = ((kk * 4 + rq) ^ (l & 7)) * 8;
      bf16x8 af[4], f1[2], f2[2];
#pragma unroll
      for (int i = 0; i < 4; ++i)
        af[i] = *(const bf16x8*)(&As[buf][0][0] + (wm + i * 16 + rl) * 64 + g);
#pragma unroll
      for (int j = 0; j < 2; ++j) {
        f1[j] = *(const bf16x8*)(&B1s[buf][0][0] + (wn + j * 16 + rl) * 64 + g);
        f2[j] = *(const bf16x8*)(&B2s[buf][0][0] + (wn + j * 16 + rl) * 64 + g);
      }
#pragma unroll
      for (int i = 0; i < 4; ++i)
#pragma unroll
        for (int j = 0; j < 2; ++j) {
          acc1[i][j] = __builtin_amdgcn_mfma_f32_16x16x32_bf16(af[i], f1[j], acc1[i][j], 0, 0, 0);
          acc2[i][j] = __builtin_amdgcn_mfma_f32_16x16x32_bf16(af[i], f2[j], acc2[i][j], 0, 0, 0);
        }
    }
  };

  const int NSTEP = ND / 64;  // 16
  loadA(0, 0); loadA(1, 1);
  loadB(0, 0); loadB(1, 1); loadB(2, 2);
  writeA(0, 0); writeB(0, 0);
  LBAR();
#pragma unroll
  for (int k = 0; k < NSTEP; ++k) {
    if (k + 2 < NSTEP) loadA(k & 1, k + 2);
    if (k + 3 < NSTEP) loadB(k % 3, k + 3);
    domfma(k & 1);
    if (k + 1 < NSTEP) {
      writeA((k + 1) & 1, (k + 1) & 1);
      writeB((k + 1) & 1, (k + 1) % 3);
      LBAR();
    }
  }

  // SwiGLU epilogue
#pragma unroll
  for (int i = 0; i < 4; ++i)
#pragma unroll
    for (int r = 0; r < 4; ++r) {
      int mrow = wm + i * 16 + rq * 4 + r;
      int m = m0 + mrow;
      if (m < cnt) {
#pragma unroll
        for (int j = 0; j < 2; ++j) {
          int col = n0 + wn + j * 16 + rl;
          float g1 = acc1[i][j][r], g2 = acc2[i][j][r];
          float hv = g1 / (1.f + expf(-g1)) * g2;
          h[(size_t)(base + m) * NH + col] = f2b(hv);
        }
      }
    }
}

// ---------------- GEMM3: out += h @ W3^T (split-K=2, atomicAdd) ----------------
__global__ __launch_bounds__(256, 3) void moe_gemm3(
    const unsigned short* __restrict__ hsrc, const float* __restrict__ W3f,
    const int* __restrict__ offsets, const int* __restrict__ token_list,
    float* __restrict__ outp)
{
  const int e = blockIdx.z & 7;
  const int kc = blockIdx.z >> 3;
  const int koff = kc * (NH / 2);   // 1792
  const int base = offsets[e], cnt = offsets[e + 1] - base;
  const int m0 = blockIdx.y * 128;
  if (m0 >= cnt) return;
  const int n0 = blockIdx.x * 64;

  __shared__ __align__(16) unsigned short As[2][128][64];
  __shared__ __align__(16) unsigned short Bs[2][64][64];
  __shared__ int rtk[128];

  const int t = threadIdx.x;
  const int l = t & 63, w = t >> 6;
  if (t < 128) {
    int mc = m0 + t; if (mc > cnt - 1) mc = cnt - 1;
    rtk[t] = token_list[base + mc];
  }
  __syncthreads();

  const int ar = t >> 1;
  const int asub0 = (t & 1) * 4;
  int arow = m0 + ar; if (arow > cnt - 1) arow = cnt - 1;
  const unsigned short* asrc = hsrc + (size_t)(base + arow) * NH + koff + asub0 * 8;
  int aw[4];
#pragma unroll
  for (int i = 0; i < 4; ++i)
    aw[i] = ar * 64 + (((asub0 + i) ^ (ar & 7)) * 8);

  const int br = t >> 2;
  const int bcol = (t & 3) * 16;
  const float* b3p = W3f + (size_t)e * ND * NH + (size_t)(n0 + br) * NH + koff + bcol;
  int bw[2];
#pragma unroll
  for (int i = 0; i < 2; ++i)
    bw[i] = br * 64 + ((((t & 3) * 2 + i) ^ (br & 7)) * 8);

  u32x4 av[2][4];
  f32x4 bv[3][4];

  auto loadA = [&](int s, int k) {
#pragma unroll
    for (int i = 0; i < 4; ++i)
      av[s][i] = *(const u32x4*)(asrc + k * 64 + i * 8);
  };
  auto loadB = [&](int s, int k) {
#pragma unroll
    for (int i = 0; i < 4; ++i)
      bv[s][i] = *(const f32x4*)(b3p + k * 64 + i * 4);
  };
  auto writeA = [&](int buf, int s) {
    unsigned short* dst = &As[buf][0][0];
#pragma unroll
    for (int i = 0; i < 4; ++i)
      *(u32x4*)(dst + aw[i]) = av[s][i];
  };
  auto writeB = [&](int buf, int s) {
    unsigned short* d = &Bs[buf][0][0];
    *(u16x8*)(d + bw[0]) = cvt8(bv[s][0], bv[s][1]);
    *(u16x8*)(d + bw[1]) = cvt8(bv[s][2], bv[s][3]);
  };

  const int wm = (w >> 1) * 64;
  const int wn = (w & 1) * 32;
  const int rl = l & 15, rq = l >> 4;
  f32x4 acc[4][2] = {};

  auto domfma = [&](int buf) {
#pragma unroll
    for (int kk = 0; kk < 2; ++kk) {
      const int g = ((kk * 4 + rq) ^ (l & 7)) * 8;
      bf16x8 af[4], bf[2];
#pragma unroll
      for (int i = 0; i < 4; ++i)
        af[i] = *(const bf16x8*)(&As[buf][0][0] + (wm + i * 16 + rl) * 64 + g);
#pragma unroll
      for (int j = 0; j < 2; ++j)
        bf[j] = *(const bf16x8*)(&Bs[buf][0][0] + (wn + j * 16 + rl) * 64 + g);
#pragma unroll
      for (int i = 0; i < 4; ++i)
#pragma unroll
        for (int j = 0; j < 2; ++j)
          acc[i][j] = __builtin_amdgcn_mfma_f32_16x16x32_bf16(af[i], bf[j], acc[i][j], 0, 0, 0);
    }
  };

  const int NSTEP = (NH / 2) / 64;  // 28
  loadA(0, 0); loadA(1, 1);
  loadB(0, 0); loadB(1, 1); loadB(2, 2);
  writeA(0, 0); writeB(0, 0);
  LBAR();
#pragma unroll
  for (int k = 0; k < NSTEP; ++k) {
    if (k + 2 < NSTEP) loadA(k & 1, k + 2);
    if (k + 3 < NSTEP) loadB(k % 3, k + 3);
    domfma(k & 1);
    if (k + 1 < NSTEP) {
      writeA((k + 1) & 1, (k + 1) & 1);
      writeB((k + 1) & 1, (k + 1) % 3);
      LBAR();
    }
  }

#pragma unroll
  for (int i = 0; i < 4; ++i)
#pragma unroll
    for (int r = 0; r < 4; ++r) {
      int mrow = wm + i * 16 + rq * 4 + r;
      int m = m0 + mrow;
      if (m < cnt) {
        int tok = rtk[mrow];
#pragma unroll
        for (int j = 0; j < 2; ++j) {
          int col = n0 + wn + j * 16 + rl;
          atomicAdd(&outp[(size_t)tok * ND + col], acc[i][j][r]);
        }
      }
    }
}

extern "C" void kernel_launch(void* const* d_in, const int* in_sizes, int n_in,
                              void* d_out, int out_size, void* d_ws, size_t ws_size,
                              hipStream_t stream)
{
  (void)in_sizes; (void)n_in; (void)out_size; (void)ws_size;
  const float* x  = (const float*)d_in[0];
  const float* Wr = (const float*)d_in[1];
  const float* W1 = (const float*)d_in[2];
  const float* W2 = (const float*)d_in[3];
  const float* W3 = (const float*)d_in[4];
  float* out = (float*)d_out;

  char* w = (char*)d_ws;
  float* probs    = (float*)(w + 0);        // 65536 B
  float* lse      = (float*)(w + 65536);    // 8192 B
  int* counts     = (int*)(w + 73728);      // 32 B
  int* cursors    = (int*)(w + 73760);      // 32 B
  int* offsets    = (int*)(w + 73792);      // 64 B
  int* expert_of  = (int*)(w + 73856);      // 8192 B
  int* token_list = (int*)(w + 82048);      // 8192 B
  unsigned short* h  = (unsigned short*)(w + 131072);            // 14680064 B
  unsigned short* xb = (unsigned short*)(w + 131072 + 14680064); // 4194304 B

  hipMemsetAsync(counts, 0, 32, stream);
  hipMemsetAsync(out, 0, (size_t)NTOK * ND * sizeof(float), stream);
  router_kernel<<<NTOK, 256, 0, stream>>>(x, Wr, probs, lse, counts, expert_of, xb);
  aux_offsets_kernel<<<1, 256, 0, stream>>>(probs, lse, counts, offsets, cursors,
                                            out + (size_t)NTOK * ND);
  scatter_kernel<<<NTOK / 256, 256, 0, stream>>>(expert_of, cursors, token_list);
  moe_gemm12<<<dim3(NH / 64, NTOK / 128, NE), 256, 0, stream>>>(
      xb, W1, W2, offsets, token_list, h);
  moe_gemm3<<<dim3(ND / 64, NTOK / 128, NE * 2), 256, 0, stream>>>(
      h, W3, offsets, token_list, out);
}

// Round 8
// 213.608 us; speedup vs baseline: 1.4151x; 1.0369x over previous
//
#include <hip/hip_runtime.h>
#include <hip/hip_bf16.h>
#include <math.h>

// MoE: B=2,S=1024,D=1024,E=8,H=3584, top-1 routing.
// router(+x->bf16) -> aux -> scatter
//  -> ggemm<GATHER>: g1=x@W1^T, g2=x@W2^T. Block=(expert,64-col panel,matrix):
//     weight panel streamed ONCE; all expert rows (CHUNK=384) resident per
//     K-step in single-buffered A (refreshed per step via global_load_lds
//     from L2-resident xb). B: 3-deep reg sets -> dbuf LDS; CBAR(4) retires
//     only the A-DMA, keeps newest B-set in flight across the barrier.
//  -> swiglu (g1 <- silu(g1)*g2)
//  -> ggemm<ATOMIC>: out += h@W3^T, split-K=4, atomicAdd f32.

#define NS 1024
#define ND 1024
#define NE 8
#define NH 3584
#define NTOK 2048
#define CHUNK 384

typedef float f32x4 __attribute__((ext_vector_type(4)));
typedef __bf16 bf16x8 __attribute__((ext_vector_type(8)));
typedef unsigned short u16x8 __attribute__((ext_vector_type(8)));

#define LBAR()  asm volatile("s_waitcnt lgkmcnt(0)\n\ts_barrier" ::: "memory")
#define CBAR(N) asm volatile("s_waitcnt vmcnt(" #N ") lgkmcnt(0)\n\ts_barrier" ::: "memory")

__device__ __forceinline__ unsigned short f2b(float f) {
  return __builtin_bit_cast(unsigned short, (__bf16)f);
}
__device__ __forceinline__ u16x8 cvt8(f32x4 a, f32x4 b) {
  u16x8 r;
  r[0] = f2b(a[0]); r[1] = f2b(a[1]); r[2] = f2b(a[2]); r[3] = f2b(a[3]);
  r[4] = f2b(b[0]); r[5] = f2b(b[1]); r[6] = f2b(b[2]); r[7] = f2b(b[3]);
  return r;
}
__device__ __forceinline__ void gl_lds16(const void* g, void* l) {
  __builtin_amdgcn_global_load_lds(
      (const __attribute__((address_space(1))) unsigned int*)g,
      (__attribute__((address_space(3))) unsigned int*)l, 16, 0, 0);
}

// ---------------- router (+ x f32 -> bf16) ----------------
__global__ __launch_bounds__(256) void router_kernel(
    const float* __restrict__ x, const float* __restrict__ Wr,
    float* __restrict__ probs, float* __restrict__ lse,
    int* __restrict__ counts, int* __restrict__ expert_of,
    unsigned short* __restrict__ xb)
{
  int n = blockIdx.x;
  int t = threadIdx.x;
  const float* xr = x + (size_t)n * ND;
  float xv[4];
#pragma unroll
  for (int j = 0; j < 4; ++j) xv[j] = xr[t + j * 256];
#pragma unroll
  for (int j = 0; j < 4; ++j)
    xb[(size_t)n * ND + t + j * 256] = f2b(xv[j]);
  float p[NE];
#pragma unroll
  for (int e = 0; e < NE; ++e) p[e] = 0.f;
#pragma unroll
  for (int j = 0; j < 4; ++j) {
    int d = t + j * 256;
#pragma unroll
    for (int e = 0; e < NE; ++e) p[e] += xv[j] * Wr[e * ND + d];
  }
#pragma unroll
  for (int e = 0; e < NE; ++e) {
#pragma unroll
    for (int o = 32; o > 0; o >>= 1) p[e] += __shfl_down(p[e], o, 64);
  }
  __shared__ float red[4][NE];
  int wid = t >> 6, lane = t & 63;
  if (lane == 0) {
#pragma unroll
    for (int e = 0; e < NE; ++e) red[wid][e] = p[e];
  }
  __syncthreads();
  if (t == 0) {
    float lg[NE];
#pragma unroll
    for (int e = 0; e < NE; ++e) lg[e] = red[0][e] + red[1][e] + red[2][e] + red[3][e];
    float m = lg[0]; int arg = 0;
#pragma unroll
    for (int e = 1; e < NE; ++e) if (lg[e] > m) { m = lg[e]; arg = e; }
    float s = 0.f, ex[NE];
#pragma unroll
    for (int e = 0; e < NE; ++e) { ex[e] = expf(lg[e] - m); s += ex[e]; }
    float inv = 1.f / s;
#pragma unroll
    for (int e = 0; e < NE; ++e) probs[n * NE + e] = ex[e] * inv;
    lse[n] = m + logf(s);
    expert_of[n] = arg;
    atomicAdd(&counts[arg], 1);
  }
}

// ---------------- aux losses + offsets ----------------
__global__ __launch_bounds__(256) void aux_offsets_kernel(
    const float* __restrict__ probs, const float* __restrict__ lse,
    const int* __restrict__ counts, int* __restrict__ offsets,
    int* __restrict__ cursors, float* __restrict__ out_aux)
{
  int t = threadIdx.x;
  float lsum = 0.f;
  for (int n = t; n < NTOK; n += 256) lsum += lse[n];
  float esum = 0.f, esq = 0.f;
  for (int i = t; i < NS * NE; i += 256) {
    float v = probs[i] + probs[NS * NE + i];
    esum += v; esq += v * v;
  }
  __shared__ float rb[3][4];
  int wid = t >> 6, lane = t & 63;
#pragma unroll
  for (int o = 32; o > 0; o >>= 1) {
    lsum += __shfl_down(lsum, o, 64);
    esum += __shfl_down(esum, o, 64);
    esq  += __shfl_down(esq, o, 64);
  }
  if (lane == 0) { rb[0][wid] = lsum; rb[1][wid] = esum; rb[2][wid] = esq; }
  __syncthreads();
  if (t == 0) {
    lsum = rb[0][0] + rb[0][1] + rb[0][2] + rb[0][3];
    esum = rb[1][0] + rb[1][1] + rb[1][2] + rb[1][3];
    esq  = rb[2][0] + rb[2][1] + rb[2][2] + rb[2][3];
    float zmean = lsum / (float)NTOK;
    float z_loss = zmean * zmean;
    const float nn = (float)(NS * NE);
    float mean = esum / nn;
    float var = (esq - esum * esum / nn) / (nn - 1.0f);
    float load_loss = var / (mean * mean);
    out_aux[0] = 1e-3f * z_loss + 1e-3f * load_loss;
    int off = 0;
#pragma unroll
    for (int e = 0; e < NE; ++e) { offsets[e] = off; cursors[e] = off; off += counts[e]; }
    offsets[NE] = off;
  }
}

// ---------------- token lists ----------------
__global__ __launch_bounds__(256) void scatter_kernel(
    const int* __restrict__ expert_of, int* __restrict__ cursors,
    int* __restrict__ token_list)
{
  int n = blockIdx.x * 256 + threadIdx.x;
  int e = expert_of[n];
  int p = atomicAdd(&cursors[e], 1);
  token_list[p] = n;
}

// ---------------- grouped GEMM, weights read once ----------------
// Block = (expert, 64-col weight panel [, matrix | K-slice]).
// A: CHUNK=384 rows single-buffered in LDS, refreshed per K-step via
//    global_load_lds (XOR-8 pre-swizzled source). Waves split 4-in-M.
// B: f32 weights, 3-deep register sets -> XOR-swizzled dbuf LDS.
// Per iter: domfma -> LBAR -> stageA(k+1) -> writeB(k+1) -> loadB(k+3)
//           -> CBAR(4) (retire A-DMA, keep newest B-set in flight).
template<int NSTEP, int LDA, int LDW, bool GATHER, bool ATOMIC>
__global__ __launch_bounds__(256, 2) void ggemm(
    const unsigned short* __restrict__ Ab,
    const float* __restrict__ Wa, const float* __restrict__ Wb,
    const int* __restrict__ offsets, const int* __restrict__ token_list,
    unsigned short* __restrict__ ga, unsigned short* __restrict__ gb,
    float* __restrict__ outp)
{
  const int e = blockIdx.z;
  const int base = offsets[e], cnt = offsets[e + 1] - base;
  if (cnt <= 0) return;
  const int n0 = blockIdx.x * 64;
  int akoff = 0;
  const float* W;
  unsigned short* g = nullptr;
  if constexpr (GATHER) {
    W = (blockIdx.y ? Wb : Wa) + (size_t)e * ((size_t)NH * ND) + (size_t)n0 * LDW;
    g = blockIdx.y ? gb : ga;
  } else {
    akoff = blockIdx.y * (NSTEP * 64);
    W = Wa + (size_t)e * ((size_t)NH * ND) + (size_t)n0 * LDW + akoff;
  }

  __shared__ __align__(16) unsigned short As[CHUNK * 64];     // 48 KB, single buf
  __shared__ __align__(16) unsigned short Bs[2][64 * 64];     // 16 KB dbuf
  __shared__ int rtk[CHUNK];

  const int t = threadIdx.x, l = t & 63, w = t >> 6;
  const int rl = l & 15, rq = l >> 4;

  for (int c0 = 0; c0 < cnt; c0 += CHUNK) {
    __syncthreads();
    for (int r = t; r < CHUNK; r += 256) {
      int mc = c0 + r; if (mc > cnt - 1) mc = cnt - 1;
      rtk[r] = token_list[base + mc];
    }
    __syncthreads();

    // A-DMA sources: wave w stages rows w*96+i*8+(l>>3); source 16B-block
    // pre-swizzled by ^(row&7) = ^(l>>3).
    const char* aSrc[12];
    {
      int r8 = l >> 3;
      int sb = (l & 7) ^ r8;
#pragma unroll
      for (int i = 0; i < 12; ++i) {
        int row = w * 96 + i * 8 + r8;
        size_t arow;
        if constexpr (GATHER) {
          arow = (size_t)rtk[row];
        } else {
          int mc = c0 + row; if (mc > cnt - 1) mc = cnt - 1;
          arow = (size_t)(base + mc);
        }
        aSrc[i] = (const char*)(Ab + arow * LDA + akoff) + sb * 16;
      }
    }
    auto stageA = [&](int k) {
      char* d = (char*)As + w * 12288;
#pragma unroll
      for (int i = 0; i < 12; ++i)
        gl_lds16(aSrc[i] + k * 128, d + i * 1024);
    };

    // B: 3 register sets, f32 -> bf16 -> swizzled LDS
    const float* bp = W + (size_t)(t >> 2) * LDW + (t & 3) * 16;
    const int br = t >> 2, c2 = (t & 3) * 2;
    const int bw0 = br * 128 + ((c2 ^ (br & 7)) * 16);
    const int bw1 = br * 128 + (((c2 + 1) ^ (br & 7)) * 16);
    f32x4 bs[3][4];
    auto loadB = [&](int s, int k) {
#pragma unroll
      for (int i = 0; i < 4; ++i) bs[s][i] = *(const f32x4*)(bp + k * 64 + i * 4);
    };
    auto writeB = [&](int buf, int s) {
      char* d = (char*)&Bs[buf][0];
      *(u16x8*)(d + bw0) = cvt8(bs[s][0], bs[s][1]);
      *(u16x8*)(d + bw1) = cvt8(bs[s][2], bs[s][3]);
    };

    f32x4 acc[6][4] = {};
    auto domfma = [&](int buf) {
#pragma unroll
      for (int kk = 0; kk < 2; ++kk) {
        const int gx = ((kk * 4 + rq) ^ (l & 7)) * 16;
        bf16x8 bf[4];
#pragma unroll
        for (int j = 0; j < 4; ++j)
          bf[j] = *(const bf16x8*)((const char*)&Bs[buf][0] + (j * 16 + rl) * 128 + gx);
#pragma unroll
        for (int i = 0; i < 6; ++i) {
          bf16x8 af = *(const bf16x8*)((const char*)As + (w * 96 + i * 16 + rl) * 128 + gx);
#pragma unroll
          for (int j = 0; j < 4; ++j)
            acc[i][j] = __builtin_amdgcn_mfma_f32_16x16x32_bf16(af, bf[j], acc[i][j], 0, 0, 0);
        }
      }
    };

    // prologue: A(0) DMA first (FIFO-oldest), then 3 B sets, publish B(0)
    stageA(0);
    loadB(0, 0); loadB(1, 1); loadB(2, 2);
    writeB(0, 0);          // auto-wait retires DMA+set0, keeps set1/set2
    LBAR();

#pragma unroll
    for (int k = 0; k < NSTEP; ++k) {
      domfma(k & 1);
      if (k + 1 == NSTEP) break;
      LBAR();                              // drain ds_reads before A overwrite
      stageA(k + 1);                       // 12 DMA (oldest vmem this iter)
      writeB((k + 1) & 1, (k + 1) % 3);    // set loaded 2 iters ago (no stall)
      if (k + 3 < NSTEP) {
        loadB(k % 3, k + 3);
        CBAR(4);                           // retire A-DMA; keep newest B-set
      } else {
        CBAR(0);                           // tail: full drain
      }
    }

    // epilogue
#pragma unroll
    for (int i = 0; i < 6; ++i) {
#pragma unroll
      for (int r = 0; r < 4; ++r) {
        int mrow = w * 96 + i * 16 + rq * 4 + r;
        int m = c0 + mrow;
        if (m < cnt) {
#pragma unroll
          for (int j = 0; j < 4; ++j) {
            int col = n0 + j * 16 + rl;
            float v = acc[i][j][r];
            if constexpr (ATOMIC) {
              atomicAdd(&outp[(size_t)rtk[mrow] * ND + col], v);
            } else {
              g[(size_t)(base + m) * NH + col] = f2b(v);
            }
          }
        }
      }
    }
  }
}

// ---------------- SwiGLU in-place: g1 <- silu(g1)*g2 ----------------
__global__ __launch_bounds__(256) void swiglu_kernel(
    unsigned short* __restrict__ g1, const unsigned short* __restrict__ g2)
{
  size_t i = ((size_t)blockIdx.x * 256 + threadIdx.x) * 8;
  u16x8 a = *(const u16x8*)(g1 + i);
  u16x8 b = *(const u16x8*)(g2 + i);
  u16x8 o;
#pragma unroll
  for (int j = 0; j < 8; ++j) {
    float av = __builtin_bit_cast(float, (unsigned int)a[j] << 16);
    float bv = __builtin_bit_cast(float, (unsigned int)b[j] << 16);
    o[j] = f2b(av / (1.f + expf(-av)) * bv);
  }
  *(u16x8*)(g1 + i) = o;
}

extern "C" void kernel_launch(void* const* d_in, const int* in_sizes, int n_in,
                              void* d_out, int out_size, void* d_ws, size_t ws_size,
                              hipStream_t stream)
{
  (void)in_sizes; (void)n_in; (void)out_size; (void)ws_size;
  const float* x  = (const float*)d_in[0];
  const float* Wr = (const float*)d_in[1];
  const float* W1 = (const float*)d_in[2];
  const float* W2 = (const float*)d_in[3];
  const float* W3 = (const float*)d_in[4];
  float* out = (float*)d_out;

  char* w = (char*)d_ws;
  float* probs    = (float*)(w + 0);        // 65536 B
  float* lse      = (float*)(w + 65536);    // 8192 B
  int* counts     = (int*)(w + 73728);      // 32 B
  int* cursors    = (int*)(w + 73760);      // 32 B
  int* offsets    = (int*)(w + 73792);      // 64 B
  int* expert_of  = (int*)(w + 73856);      // 8192 B
  int* token_list = (int*)(w + 82048);      // 8192 B
  unsigned short* g1 = (unsigned short*)(w + 131072);            // 14680064 B (-> h)
  unsigned short* g2 = g1 + (size_t)NTOK * NH;                   // 14680064 B
  unsigned short* xb = (unsigned short*)((char*)g2 + (size_t)NTOK * NH * 2); // 4 MB

  hipMemsetAsync(counts, 0, 32, stream);
  hipMemsetAsync(out, 0, (size_t)NTOK * ND * sizeof(float), stream);
  router_kernel<<<NTOK, 256, 0, stream>>>(x, Wr, probs, lse, counts, expert_of, xb);
  aux_offsets_kernel<<<1, 256, 0, stream>>>(probs, lse, counts, offsets, cursors,
                                            out + (size_t)NTOK * ND);
  scatter_kernel<<<NTOK / 256, 256, 0, stream>>>(expert_of, cursors, token_list);
  // g1 = x@W1^T, g2 = x@W2^T : weights read once
  ggemm<ND / 64, ND, ND, true, false><<<dim3(NH / 64, 2, NE), 256, 0, stream>>>(
      xb, W1, W2, offsets, token_list, g1, g2, nullptr);
  swiglu_kernel<<<(NTOK * NH) / (256 * 8), 256, 0, stream>>>(g1, g2);
  // out += h@W3^T : split-K=4, W3 read once
  ggemm<(NH / 4) / 64, NH, NH, false, true><<<dim3(ND / 64, 4, NE), 256, 0, stream>>>(
      g1, W3, nullptr, offsets, token_list, nullptr, nullptr, out);
}